// Round 3
// baseline (207.894 us; speedup 1.0000x reference)
//
#include <hip/hip_runtime.h>

typedef unsigned short ushort_t;

#define M_DIM 1024   // 2*512 rows of x
#define N_DIM 4096   // OUT_F
#define K_DIM 4096   // IN_F
#define NFREQ 10000
constexpr float SCALE = 150.0f / 64.0f;   // 150 / sqrt(4096)

typedef __bf16 bf16x8_t  __attribute__((ext_vector_type(8)));
typedef float  f32x16_t  __attribute__((ext_vector_type(16)));

__device__ inline ushort_t f2bf(float f) {
  union { float f; unsigned u; } v; v.f = f;
  unsigned r = v.u + 0x7fffu + ((v.u >> 16) & 1u);   // RNE
  return (ushort_t)(r >> 16);
}

// ---------------------------------------------------------------------------
// Kernel 1: W' = bf16( weight + s * iwht(scatter(spectrum,idx)) ), plus
// x fp32->bf16 folded in as grid-y slice 32.
// R3 change: build_w4 was GRID-limited (64x17=1088 blocks = 4.25/CU -> max
// ~17 waves/CU; measured 34.6% occupancy, 1.55 TB/s). Thread now covers
// 4 cols x 8 rows (walsh8 signs), y-slices 16 -> 32, grid 64x33 = 2112
// blocks = 8.25/CU -> 100% theoretical occupancy (LDS 17.4KB*8 = 139KB OK).
// R2's 16-deep VGPR prefetch is REVERTED (VGPR 80 killed occupancy: 66us).
// ---------------------------------------------------------------------------
__global__ __launch_bounds__(256) void build_w4(
    const float* __restrict__ weight,
    const float* __restrict__ spectrum,
    const int* __restrict__ idx,          // [2][NFREQ]: row 0 = r (out), row 1 = c (in)
    const float* __restrict__ x,
    ushort_t* __restrict__ wb,
    ushort_t* __restrict__ xb) {
  // ---- folded cvt_x slice ----
  if (blockIdx.y == 32) {
    int flat = blockIdx.x * 256 + threadIdx.x;    // 16384 threads
#pragma unroll 4
    for (int k = 0; k < 64; ++k) {
      int i = flat + k * 16384;                   // M*K/4 = 1048576 float4s
      float4 v = ((const float4*)x)[i];
      ushort4 o;
      o.x = f2bf(v.x); o.y = f2bf(v.y); o.z = f2bf(v.z); o.w = f2bf(v.w);
      ((ushort4*)xb)[i] = o;
    }
    return;
  }

  constexpr int CAP = 1024;
  __shared__ unsigned e_raw[CAP];   // (dc<<26)|(j<<12)|r
  __shared__ float    v_raw[CAP];
  __shared__ uint2    ev_srt[CAP];  // .x = packed meta, .y = float bits
  __shared__ int cnt;
  __shared__ int cstart[65];
  __shared__ int coff[64];
  __shared__ int ccnt[64];
  __shared__ unsigned walsh8[8];    // walsh8[m] bit j = parity(j & m), j<8

  const int tid = threadIdx.x;
  const int ci0 = blockIdx.x * 64;
  const int o0  = blockIdx.y * 128;

  if (tid == 0) cnt = 0;
  if (tid < 64) ccnt[tid] = 0;
  if (tid < 8) {
    unsigned m = tid;
    unsigned w = (m & 1 ? 0xAAu : 0u) ^ (m & 2 ? 0xCCu : 0u)
               ^ (m & 4 ? 0xF0u : 0u);
    walsh8[m] = w;
  }
  __syncthreads();

  // Phase 1: collect this group's entries
  for (int j = tid; j < NFREQ; j += 256) {
    int c = idx[NFREQ + j];
    if ((c >> 6) == (int)blockIdx.x) {
      int p = atomicAdd(&cnt, 1);
      if (p < CAP) {
        e_raw[p] = ((unsigned)(c & 63) << 26) | ((unsigned)j << 12) | (unsigned)idx[j];
        v_raw[p] = spectrum[j];
        atomicAdd(&ccnt[c & 63], 1);
      }
    }
  }
  __syncthreads();
  const int n = cnt < CAP ? cnt : CAP;

  // Phase 2: prefix sum over 64 column counts (wave 0), then scatter sorted
  if (tid < 64) {
    int v = ccnt[tid];
    int s = v;
    for (int d = 1; d < 64; d <<= 1) {
      int o = __shfl_up(s, d, 64);
      if (tid >= d) s += o;
    }
    cstart[tid + 1] = s;
    if (tid == 0) cstart[0] = 0;
    coff[tid] = s - v;   // exclusive
  }
  __syncthreads();
  for (int e = tid; e < n; e += 256) {
    unsigned w = e_raw[e];
    int dc = w >> 26;
    int p = atomicAdd(&coff[dc], 1);
    ev_srt[p] = make_uint2(w, __float_as_uint(v_raw[e]));
  }
  __syncthreads();

  // Phase 3: last-wins dedup within each column bucket (LDS-local)
  for (int e = tid; e < n; e += 256) {
    uint2 ev = ev_srt[e];
    int dc = ev.x >> 26;
    unsigned r = ev.x & 0xFFFu, j = (ev.x >> 12) & 0x3FFFu;
    int s0 = cstart[dc], e0 = cstart[dc + 1];
    bool dead = false;
    for (int p = s0; p < e0; ++p) {
      unsigned w2 = ev_srt[p].x;
      if ((w2 & 0xFFFu) == r && ((w2 >> 12) & 0x3FFFu) > j) dead = true;
    }
    if (dead) ev_srt[e].y = 0u;   // +0.0f: additive no-op == excluded
  }
  __syncthreads();

  // Phase 4: thread = 4 consecutive cols x 8 CONTIGUOUS rows, entry-outer.
  // Sign for row obase+j (obase multiple of 8, j<8):
  //   parity((obase|j) & r) = parity(obase & r) ^ parity(j & (r & 7))
  const int dc0   = (tid & 15) * 4;
  const int rof   = tid >> 4;          // 0..15
  const int obase = o0 + rof * 8;

  float acc[4][8];
#pragma unroll
  for (int c = 0; c < 4; ++c)
#pragma unroll
    for (int j = 0; j < 8; ++j) acc[c][j] = 0.0f;

#pragma unroll
  for (int c = 0; c < 4; ++c) {
    const int s = cstart[dc0 + c], e = cstart[dc0 + c + 1];
    for (int p = s; p < e; ++p) {
      uint2 ev = ev_srt[p];                       // one ds_read_b64 per entry
      unsigned r = ev.x & 0xFFFu;
      unsigned W = walsh8[r & 7u];                // 8-row sign pattern
      unsigned sx = ev.y ^ ((unsigned)(__popc(obase & r) & 1) << 31);  // ±v base sign
#pragma unroll
      for (int j = 0; j < 8; ++j) {
        acc[c][j] += __uint_as_float(sx ^ ((W << (31 - j)) & 0x80000000u));
      }
    }
  }

  // Epilogue: FULL unroll so all acc indices are compile-time (VGPR-resident;
  // partial unroll demotes acc to scratch — R4 regression).
  size_t g = (size_t)obase * K_DIM + ci0 + dc0;
#pragma unroll
  for (int j = 0; j < 8; ++j) {
    float4 w4 = *(const float4*)&weight[g];
    ushort4 ov;
    ov.x = f2bf(w4.x + SCALE * acc[0][j]);
    ov.y = f2bf(w4.y + SCALE * acc[1][j]);
    ov.z = f2bf(w4.z + SCALE * acc[2][j]);
    ov.w = f2bf(w4.w + SCALE * acc[3][j]);
    *(ushort4*)&wb[g] = ov;
    g += K_DIM;
  }
}

// ---------------------------------------------------------------------------
// Kernel 2: C[M,N] = A[M,K] * B[N,K]^T  (bf16 in, fp32 out), split-K via z.
// 128x128 tile, BK=64, XOR-swizzled LDS, global_load_lds 16B staging,
// inner op = mfma_f32_32x32x16_bf16 (wave tile 64x64 as 2x2 of 32x32).
// A/B frag: row = lane&31, k = (lane>>5)*8 + t (one b128 per frag).
// C/D: col = lane&31, row = (reg&3) + 8*(reg>>2) + 4*(lane>>5).
// XCD-aware 2D-chunk blockIdx swizzle (kept from R2): one XCD's 32 blocks
// share 4 A-panels + 8 B-panels (3 MB, fits 4 MB per-XCD L2).
// ---------------------------------------------------------------------------
__global__ __launch_bounds__(256) void gemm_bt(
    const ushort_t* __restrict__ A,   // xb [M,K]
    const ushort_t* __restrict__ B,   // wb [N,K]
    float* __restrict__ C0,
    float* __restrict__ C1,
    int klen) {
  constexpr int BM = 128, BN = 128, BK = 64;
  __shared__ __align__(16) ushort_t As[BM * BK];   // 16 KB
  __shared__ __align__(16) ushort_t Bs[BN * BK];   // 16 KB

  const int tid  = threadIdx.x;
  const int wave = tid >> 6, lane = tid & 63;
  const int wrow = wave >> 1, wcol = wave & 1;
  const int l32  = lane & 31, half = lane >> 5;

  // XCD-aware swizzle (bijective on the fixed 32x8 xy-grid)
  const int fid = blockIdx.y * 32 + blockIdx.x;    // 0..255 within z-slice
  const int xcd = fid & 7, w8 = fid >> 3;          // xcd chunk, index in chunk
  const int sx = w8 & 7, sy = w8 >> 3;             // 8x * 4y within chunk
  const int cx = xcd & 3, cy = xcd >> 2;           // chunk grid 4x * 2y
  const int bn = (cx * 8 + sx) * BN;
  const int bm = (cy * 4 + sy) * BM;

  const int kbeg = blockIdx.z * klen;
  float* __restrict__ dst = blockIdx.z == 0
      ? C0 : C1 + (size_t)(blockIdx.z - 1) * M_DIM * N_DIM;

  const int srow8 = lane >> 3;          // staging: row within chunk, 0..7
  const int sq    = lane & 7;           // 16B slot within row, 0..7

  f32x16_t acc[2][2] = {};

  for (int kt = kbeg; kt < kbeg + klen; kt += BK) {
#pragma unroll
    for (int c = 0; c < 4; ++c) {
      int ch = wave * 4 + c;            // wave-uniform
      int gr = ch * 8 + srow8;          // tile row 0..127
      int qg = sq ^ (gr & 7);           // swizzled source quad
      const ushort_t* ga = A + (size_t)(bm + gr) * K_DIM + kt + qg * 8;
      __builtin_amdgcn_global_load_lds(
          (const __attribute__((address_space(1))) void*)ga,
          (__attribute__((address_space(3))) void*)&As[ch * 512], 16, 0, 0);
      const ushort_t* gb = B + (size_t)(bn + gr) * K_DIM + kt + qg * 8;
      __builtin_amdgcn_global_load_lds(
          (const __attribute__((address_space(1))) void*)gb,
          (__attribute__((address_space(3))) void*)&Bs[ch * 512], 16, 0, 0);
    }
    __syncthreads();

    // fragment loads: frag (mi,h) = A rows [wrow*64+mi*32 .. +32), k half*8+h*16
    bf16x8_t af[2][4], bfr[2][4];
#pragma unroll
    for (int mi = 0; mi < 2; ++mi) {
#pragma unroll
      for (int h = 0; h < 4; ++h) {
        int q = h * 2 + half;           // 16B slot index along k
        int ar = wrow * 64 + mi * 32 + l32;
        af[mi][h]  = *(const bf16x8_t*)&As[ar * BK + ((q ^ (ar & 7)) * 8)];
        int br = wcol * 64 + mi * 32 + l32;
        bfr[mi][h] = *(const bf16x8_t*)&Bs[br * BK + ((q ^ (br & 7)) * 8)];
      }
    }
#pragma unroll
    for (int h = 0; h < 4; ++h)
#pragma unroll
      for (int mi = 0; mi < 2; ++mi)
#pragma unroll
        for (int nj = 0; nj < 2; ++nj)
          acc[mi][nj] = __builtin_amdgcn_mfma_f32_32x32x16_bf16(
              af[mi][h], bfr[nj][h], acc[mi][nj], 0, 0, 0);
    __syncthreads();
  }

  // epilogue: col = lane&31, row = (reg&3) + 8*(reg>>2) + 4*half
#pragma unroll
  for (int mi = 0; mi < 2; ++mi) {
#pragma unroll
    for (int nj = 0; nj < 2; ++nj) {
      int col  = bn + wcol * 64 + nj * 32 + l32;
      int rwb  = bm + wrow * 64 + mi * 32 + 4 * half;
#pragma unroll
      for (int reg = 0; reg < 16; ++reg) {
        int row = rwb + (reg & 3) + 8 * (reg >> 2);
        dst[(size_t)row * N_DIM + col] = acc[mi][nj][reg];
      }
    }
  }
}

// ---------------------------------------------------------------------------
// Kernel 3: out += sum of npart partial arrays (float4)
// ---------------------------------------------------------------------------
__global__ __launch_bounds__(256) void reduce_n(float* __restrict__ out,
                                                const float* __restrict__ part,
                                                int npart) {
  int i = blockIdx.x * 256 + threadIdx.x;
  float4 a = ((const float4*)out)[i];
  for (int t = 0; t < npart; ++t) {
    float4 b = ((const float4*)(part + (size_t)t * M_DIM * N_DIM))[i];
    a.x += b.x; a.y += b.y; a.z += b.z; a.w += b.w;
  }
  ((float4*)out)[i] = a;
}

extern "C" void kernel_launch(void* const* d_in, const int* in_sizes, int n_in,
                              void* d_out, int out_size, void* d_ws, size_t ws_size,
                              hipStream_t stream) {
  const float* x        = (const float*)d_in[0];   // [2,512,4096]
  const float* weight   = (const float*)d_in[1];   // [4096,4096]
  const float* spectrum = (const float*)d_in[2];   // [10000]
  const int*   indices  = (const int*)d_in[3];     // [2,10000]
  float* out = (float*)d_out;                      // [2,512,4096]

  char* ws = (char*)d_ws;
  const size_t WB_BYTES = (size_t)N_DIM * K_DIM * 2;   // 32 MB
  const size_t XB_BYTES = (size_t)M_DIM * K_DIM * 2;   //  8 MB
  const size_t P1_BYTES = (size_t)M_DIM * N_DIM * 4;   // 16 MB per partial

  ushort_t* wb = (ushort_t*)ws;
  ushort_t* xb = (ushort_t*)(ws + WB_BYTES);
  float* part = (float*)(ws + WB_BYTES + XB_BYTES);

  // zsplit=2 measured better than 4 (R1: 48+13 vs R0: 51.5+8 us)
  int zsplit = (ws_size >= WB_BYTES + XB_BYTES + P1_BYTES) ? 2 : 1;

  // build W' (y=0..31) + convert x (y=32) in one dispatch
  build_w4<<<dim3(64, 33), 256, 0, stream>>>(weight, spectrum, indices, x, wb, xb);

  gemm_bt<<<dim3(N_DIM / 128, M_DIM / 128, zsplit), 256, 0, stream>>>(
      xb, wb, out, part, K_DIM / zsplit);
  if (zsplit > 1)
    reduce_n<<<(M_DIM * N_DIM / 4) / 256, 256, 0, stream>>>(out, part, zsplit - 1);
}

// Round 4
// 185.825 us; speedup vs baseline: 1.1188x; 1.1188x over previous
//
#include <hip/hip_runtime.h>

typedef unsigned short ushort_t;

#define M_DIM 1024   // 2*512 rows of x
#define N_DIM 4096   // OUT_F
#define K_DIM 4096   // IN_F
#define NFREQ 10000
constexpr float SCALE = 150.0f / 64.0f;   // 150 / sqrt(4096)

typedef __bf16 bf16x8_t  __attribute__((ext_vector_type(8)));
typedef float  f32x16_t  __attribute__((ext_vector_type(16)));

// Native RNE f32->bf16 (gfx950 v_cvt_pk_bf16_f32 via compiler; R4 change —
// the hand-rolled bit-twiddle RNE was ~5 VALU/elem, ~30% of build_w4's
// instruction stream. m240: compiler codegen for casts is good.)
__device__ inline ushort_t f2bf(float f) {
  union { __bf16 h; ushort_t u; } v;
  v.h = (__bf16)f;
  return v.u;
}

// ---------------------------------------------------------------------------
// Kernel 1: W' = bf16( weight + s * iwht(scatter(spectrum,idx)) ), plus
// x fp32->bf16 folded in as grid-y slice 0 (R4: cvt FIRST — y is the slow
// dispatch dim, so y==16 made the 64 cvt blocks a serial tail on an
// otherwise-idle machine; y==0 removes the tail).
// Structure = R0 best-known (16 W-slices, walsh16, acc[4][16]): R1 proved
// phases 1-3 are only ~5us of the kernel; R2 (ILP prefetch) and R3 (more
// slices) both regressed. Kernel is VALU+stall bound -> cut VALU via f2bf.
// ---------------------------------------------------------------------------
__global__ __launch_bounds__(256) void build_w4(
    const float* __restrict__ weight,
    const float* __restrict__ spectrum,
    const int* __restrict__ idx,          // [2][NFREQ]: row 0 = r (out), row 1 = c (in)
    const float* __restrict__ x,
    ushort_t* __restrict__ wb,
    ushort_t* __restrict__ xb) {
  // ---- folded cvt_x slice (dispatched first) ----
  if (blockIdx.y == 0) {
    int flat = blockIdx.x * 256 + threadIdx.x;    // 16384 threads
#pragma unroll 4
    for (int k = 0; k < 64; ++k) {
      int i = flat + k * 16384;                   // M*K/4 = 1048576 float4s
      float4 v = ((const float4*)x)[i];
      ushort4 o;
      o.x = f2bf(v.x); o.y = f2bf(v.y); o.z = f2bf(v.z); o.w = f2bf(v.w);
      ((ushort4*)xb)[i] = o;
    }
    return;
  }

  constexpr int CAP = 1024;
  __shared__ unsigned e_raw[CAP];   // (dc<<26)|(j<<12)|r
  __shared__ float    v_raw[CAP];
  __shared__ uint2    ev_srt[CAP];  // .x = packed meta, .y = float bits
  __shared__ int cnt;
  __shared__ int cstart[65];
  __shared__ int coff[64];
  __shared__ int ccnt[64];
  __shared__ unsigned walsh16[16];  // walsh16[m] bit j = parity(j & m)

  const int tid = threadIdx.x;
  const int ci0 = blockIdx.x * 64;
  const int o0  = (blockIdx.y - 1) * 256;

  if (tid == 0) cnt = 0;
  if (tid < 64) ccnt[tid] = 0;
  if (tid < 16) {
    unsigned m = tid;
    unsigned w = (m & 1 ? 0xAAAAu : 0u) ^ (m & 2 ? 0xCCCCu : 0u)
               ^ (m & 4 ? 0xF0F0u : 0u) ^ (m & 8 ? 0xFF00u : 0u);
    walsh16[m] = w;
  }
  __syncthreads();

  // Phase 1: collect this group's entries
  for (int j = tid; j < NFREQ; j += 256) {
    int c = idx[NFREQ + j];
    if ((c >> 6) == (int)blockIdx.x) {
      int p = atomicAdd(&cnt, 1);
      if (p < CAP) {
        e_raw[p] = ((unsigned)(c & 63) << 26) | ((unsigned)j << 12) | (unsigned)idx[j];
        v_raw[p] = spectrum[j];
        atomicAdd(&ccnt[c & 63], 1);
      }
    }
  }
  __syncthreads();
  const int n = cnt < CAP ? cnt : CAP;

  // Phase 2: prefix sum over 64 column counts (wave 0), then scatter sorted
  if (tid < 64) {
    int v = ccnt[tid];
    int s = v;
    for (int d = 1; d < 64; d <<= 1) {
      int o = __shfl_up(s, d, 64);
      if (tid >= d) s += o;
    }
    cstart[tid + 1] = s;
    if (tid == 0) cstart[0] = 0;
    coff[tid] = s - v;   // exclusive
  }
  __syncthreads();
  for (int e = tid; e < n; e += 256) {
    unsigned w = e_raw[e];
    int dc = w >> 26;
    int p = atomicAdd(&coff[dc], 1);
    ev_srt[p] = make_uint2(w, __float_as_uint(v_raw[e]));
  }
  __syncthreads();

  // Phase 3: last-wins dedup within each column bucket (LDS-local)
  for (int e = tid; e < n; e += 256) {
    uint2 ev = ev_srt[e];
    int dc = ev.x >> 26;
    unsigned r = ev.x & 0xFFFu, j = (ev.x >> 12) & 0x3FFFu;
    int s0 = cstart[dc], e0 = cstart[dc + 1];
    bool dead = false;
    for (int p = s0; p < e0; ++p) {
      unsigned w2 = ev_srt[p].x;
      if ((w2 & 0xFFFu) == r && ((w2 >> 12) & 0x3FFFu) > j) dead = true;
    }
    if (dead) ev_srt[e].y = 0u;   // +0.0f: additive no-op == excluded
  }
  __syncthreads();

  // Phase 4: thread = 4 consecutive cols x 16 CONTIGUOUS rows, entry-outer.
  const int dc0   = (tid & 15) * 4;
  const int rof   = tid >> 4;
  const int obase = o0 + rof * 16;

  float acc[4][16];
#pragma unroll
  for (int c = 0; c < 4; ++c)
#pragma unroll
    for (int j = 0; j < 16; ++j) acc[c][j] = 0.0f;

#pragma unroll
  for (int c = 0; c < 4; ++c) {
    const int s = cstart[dc0 + c], e = cstart[dc0 + c + 1];
    for (int p = s; p < e; ++p) {
      uint2 ev = ev_srt[p];                       // one ds_read_b64 per entry
      unsigned r = ev.x & 0xFFFu;
      unsigned W = walsh16[r & 15u];              // 16-row sign pattern
      unsigned sx = ev.y ^ ((unsigned)(__popc(obase & r) & 1) << 31);  // ±v base sign
#pragma unroll
      for (int j = 0; j < 16; ++j) {
        acc[c][j] += __uint_as_float(sx ^ ((W << (31 - j)) & 0x80000000u));
      }
    }
  }

  // Epilogue: FULL unroll so all acc indices are compile-time (VGPR-resident;
  // partial unroll demotes acc to scratch — R4 regression).
  size_t g = (size_t)obase * K_DIM + ci0 + dc0;
#pragma unroll
  for (int j = 0; j < 16; ++j) {
    float4 w4 = *(const float4*)&weight[g];
    ushort4 ov;
    ov.x = f2bf(w4.x + SCALE * acc[0][j]);
    ov.y = f2bf(w4.y + SCALE * acc[1][j]);
    ov.z = f2bf(w4.z + SCALE * acc[2][j]);
    ov.w = f2bf(w4.w + SCALE * acc[3][j]);
    *(ushort4*)&wb[g] = ov;
    g += K_DIM;
  }
}

// ---------------------------------------------------------------------------
// Kernel 2: C[M,N] = A[M,K] * B[N,K]^T  (bf16 in, fp32 out), split-K via z.
// 128x128 tile, BK=64, XOR-swizzled LDS, global_load_lds 16B staging,
// inner op = mfma_f32_32x32x16_bf16 (wave tile 64x64 as 2x2 of 32x32).
// A/B frag: row = lane&31, k = (lane>>5)*8 + t (one b128 per frag).
// C/D: col = lane&31, row = (reg&3) + 8*(reg>>2) + 4*(lane>>5).
// XCD-aware 2D-chunk blockIdx swizzle (kept from R2): one XCD's 32 blocks
// share 4 A-panels + 8 B-panels (3 MB, fits 4 MB per-XCD L2).
// ---------------------------------------------------------------------------
__global__ __launch_bounds__(256) void gemm_bt(
    const ushort_t* __restrict__ A,   // xb [M,K]
    const ushort_t* __restrict__ B,   // wb [N,K]
    float* __restrict__ C0,
    float* __restrict__ C1,
    int klen) {
  constexpr int BM = 128, BN = 128, BK = 64;
  __shared__ __align__(16) ushort_t As[BM * BK];   // 16 KB
  __shared__ __align__(16) ushort_t Bs[BN * BK];   // 16 KB

  const int tid  = threadIdx.x;
  const int wave = tid >> 6, lane = tid & 63;
  const int wrow = wave >> 1, wcol = wave & 1;
  const int l32  = lane & 31, half = lane >> 5;

  // XCD-aware swizzle (bijective on the fixed 32x8 xy-grid)
  const int fid = blockIdx.y * 32 + blockIdx.x;    // 0..255 within z-slice
  const int xcd = fid & 7, w8 = fid >> 3;          // xcd chunk, index in chunk
  const int sx = w8 & 7, sy = w8 >> 3;             // 8x * 4y within chunk
  const int cx = xcd & 3, cy = xcd >> 2;           // chunk grid 4x * 2y
  const int bn = (cx * 8 + sx) * BN;
  const int bm = (cy * 4 + sy) * BM;

  const int kbeg = blockIdx.z * klen;
  float* __restrict__ dst = blockIdx.z == 0
      ? C0 : C1 + (size_t)(blockIdx.z - 1) * M_DIM * N_DIM;

  const int srow8 = lane >> 3;          // staging: row within chunk, 0..7
  const int sq    = lane & 7;           // 16B slot within row, 0..7

  f32x16_t acc[2][2] = {};

  for (int kt = kbeg; kt < kbeg + klen; kt += BK) {
#pragma unroll
    for (int c = 0; c < 4; ++c) {
      int ch = wave * 4 + c;            // wave-uniform
      int gr = ch * 8 + srow8;          // tile row 0..127
      int qg = sq ^ (gr & 7);           // swizzled source quad
      const ushort_t* ga = A + (size_t)(bm + gr) * K_DIM + kt + qg * 8;
      __builtin_amdgcn_global_load_lds(
          (const __attribute__((address_space(1))) void*)ga,
          (__attribute__((address_space(3))) void*)&As[ch * 512], 16, 0, 0);
      const ushort_t* gb = B + (size_t)(bn + gr) * K_DIM + kt + qg * 8;
      __builtin_amdgcn_global_load_lds(
          (const __attribute__((address_space(1))) void*)gb,
          (__attribute__((address_space(3))) void*)&Bs[ch * 512], 16, 0, 0);
    }
    __syncthreads();

    // fragment loads: frag (mi,h) = A rows [wrow*64+mi*32 .. +32), k half*8+h*16
    bf16x8_t af[2][4], bfr[2][4];
#pragma unroll
    for (int mi = 0; mi < 2; ++mi) {
#pragma unroll
      for (int h = 0; h < 4; ++h) {
        int q = h * 2 + half;           // 16B slot index along k
        int ar = wrow * 64 + mi * 32 + l32;
        af[mi][h]  = *(const bf16x8_t*)&As[ar * BK + ((q ^ (ar & 7)) * 8)];
        int br = wcol * 64 + mi * 32 + l32;
        bfr[mi][h] = *(const bf16x8_t*)&Bs[br * BK + ((q ^ (br & 7)) * 8)];
      }
    }
#pragma unroll
    for (int h = 0; h < 4; ++h)
#pragma unroll
      for (int mi = 0; mi < 2; ++mi)
#pragma unroll
        for (int nj = 0; nj < 2; ++nj)
          acc[mi][nj] = __builtin_amdgcn_mfma_f32_32x32x16_bf16(
              af[mi][h], bfr[nj][h], acc[mi][nj], 0, 0, 0);
    __syncthreads();
  }

  // epilogue: col = lane&31, row = (reg&3) + 8*(reg>>2) + 4*half
#pragma unroll
  for (int mi = 0; mi < 2; ++mi) {
#pragma unroll
    for (int nj = 0; nj < 2; ++nj) {
      int col  = bn + wcol * 64 + nj * 32 + l32;
      int rwb  = bm + wrow * 64 + mi * 32 + 4 * half;
#pragma unroll
      for (int reg = 0; reg < 16; ++reg) {
        int row = rwb + (reg & 3) + 8 * (reg >> 2);
        dst[(size_t)row * N_DIM + col] = acc[mi][nj][reg];
      }
    }
  }
}

// ---------------------------------------------------------------------------
// Kernel 3: out += sum of npart partial arrays (float4)
// ---------------------------------------------------------------------------
__global__ __launch_bounds__(256) void reduce_n(float* __restrict__ out,
                                                const float* __restrict__ part,
                                                int npart) {
  int i = blockIdx.x * 256 + threadIdx.x;
  float4 a = ((const float4*)out)[i];
  for (int t = 0; t < npart; ++t) {
    float4 b = ((const float4*)(part + (size_t)t * M_DIM * N_DIM))[i];
    a.x += b.x; a.y += b.y; a.z += b.z; a.w += b.w;
  }
  ((float4*)out)[i] = a;
}

extern "C" void kernel_launch(void* const* d_in, const int* in_sizes, int n_in,
                              void* d_out, int out_size, void* d_ws, size_t ws_size,
                              hipStream_t stream) {
  const float* x        = (const float*)d_in[0];   // [2,512,4096]
  const float* weight   = (const float*)d_in[1];   // [4096,4096]
  const float* spectrum = (const float*)d_in[2];   // [10000]
  const int*   indices  = (const int*)d_in[3];     // [2,10000]
  float* out = (float*)d_out;                      // [2,512,4096]

  char* ws = (char*)d_ws;
  const size_t WB_BYTES = (size_t)N_DIM * K_DIM * 2;   // 32 MB
  const size_t XB_BYTES = (size_t)M_DIM * K_DIM * 2;   //  8 MB
  const size_t P1_BYTES = (size_t)M_DIM * N_DIM * 4;   // 16 MB per partial

  ushort_t* wb = (ushort_t*)ws;
  ushort_t* xb = (ushort_t*)(ws + WB_BYTES);
  float* part = (float*)(ws + WB_BYTES + XB_BYTES);

  // zsplit=2 measured better than 4 (R1: 48+13 vs R0: 51.5+8 us)
  int zsplit = (ws_size >= WB_BYTES + XB_BYTES + P1_BYTES) ? 2 : 1;

  // convert x (y=0, dispatched first) + build W' (y=1..16) in one dispatch
  build_w4<<<dim3(64, 17), 256, 0, stream>>>(weight, spectrum, indices, x, wb, xb);

  gemm_bt<<<dim3(N_DIM / 128, M_DIM / 128, zsplit), 256, 0, stream>>>(
      xb, wb, out, part, K_DIM / zsplit);
  if (zsplit > 1)
    reduce_n<<<(M_DIM * N_DIM / 4) / 256, 256, 0, stream>>>(out, part, zsplit - 1);
}